// Round 3
// baseline (776.494 us; speedup 1.0000x reference)
//
#include <hip/hip_runtime.h>
#include <hip/hip_bf16.h>
#include <cstdint>

// BinaryMLP fused forward, round 3: barrier-free per-wave design (round-2
// design, compile fix: nontemporal loads use native ext_vector float4).
// Each wave owns 32 rows x all 128 cols -> layers chain within a wave with a
// wave-private LDS h-buffer (no __syncthreads at all). x A-frags are loaded
// directly from global (nontemporal) and converted fp32->bf16 in registers.
// Weights binarized/permuted by prep into d_ws (unchanged layout).

typedef __attribute__((ext_vector_type(8))) short bf16x8;   // 8 bf16 (4 VGPRs)
typedef __attribute__((ext_vector_type(4))) float f32x4;    // MFMA accumulator
typedef __attribute__((ext_vector_type(4))) float vf4;      // native float4

typedef unsigned short u16;
typedef unsigned int u32;

// ws element offsets (bf16 units)
#define WS_W1 0        // [128][224]  straight, zero-padded k>=196
#define WS_W2 28672    // [128][128]  k-permuted
#define WS_W3 45056    // [128][128]  k-permuted
#define WS_W4 61440    // [16][128]   k-permuted, rows 10..15 zero
#define WS_TOTAL 63488

#define HSTR 272       // h-buffer row stride bytes (128 bf16 + 16B pad)

__device__ __forceinline__ u32 bf16_rne(float x) {
  u32 u = __float_as_uint(x);
  return (u + 0x7FFFu + ((u >> 16) & 1u)) >> 16;
}

// pack two fp32 -> (lo,hi) bf16 pair with RNE (v_cvt_pk_bf16_f32 on gfx950)
__device__ __forceinline__ u32 pack2(float a, float b) {
  __hip_bfloat162 p = __float22bfloat162_rn(make_float2(a, b));
  return *(u32*)&p;
}

__device__ __forceinline__ u16 sign_bf16(float v) {
  return (v > 0.f) ? 0x3F80u : ((v < 0.f) ? 0xBF80u : 0u);
}

// inverse column permutation: physical p -> logical k
__device__ __forceinline__ int kperm_inv(int p) {
  return ((p & 31) >> 1) + ((p & 1) << 4) + ((p >> 5) << 5);
}

__global__ __launch_bounds__(256) void prep_kernel(
    const float* __restrict__ W1, const float* __restrict__ W2,
    const float* __restrict__ W3, const float* __restrict__ W4,
    u16* __restrict__ ws) {
  int idx = blockIdx.x * 256 + threadIdx.x;   // grid 248 -> 63488 threads exact
  if (idx < WS_W2) {
    int n = idx / 224, k = idx - n * 224;
    float v = (k < 196) ? W1[n * 196 + k] : 0.f;
    ws[idx] = (k < 196) ? sign_bf16(v) : 0u;
  } else if (idx < WS_W3) {
    int j = idx - WS_W2; int n = j >> 7, p = j & 127;
    ws[idx] = sign_bf16(W2[(n << 7) + kperm_inv(p)]);
  } else if (idx < WS_W4) {
    int j = idx - WS_W3; int n = j >> 7, p = j & 127;
    ws[idx] = sign_bf16(W3[(n << 7) + kperm_inv(p)]);
  } else if (idx < WS_TOTAL) {
    int j = idx - WS_W4; int c = j >> 7, p = j & 127;
    ws[idx] = (c < 10) ? (u16)bf16_rne(W4[(c << 7) + kperm_inv(p)]) : 0u;
  }
}

__device__ __forceinline__ bf16x8 cvt_frag(vf4 v0, vf4 v1) {
  union { bf16x8 f; u32 u[4]; } r;
  r.u[0] = pack2(v0.x, v0.y);
  r.u[1] = pack2(v0.z, v0.w);
  r.u[2] = pack2(v1.x, v1.y);
  r.u[3] = pack2(v1.z, v1.w);
  return r.f;
}

// bias + relu + packed-perm bf16 write of a [32 rows][128 cols] result into
// the wave-private h buffer. Pack pairs (g*32+m, g*32+16+m) -> one b32 at
// physical group offset g*64 (k-perm matches prep's weight permutation).
__device__ __forceinline__ void epilogue_relu_pack(
    char* hb, const f32x4 acc[2][8], const float* __restrict__ bias,
    int m, int q) {
#pragma unroll
  for (int rt = 0; rt < 2; ++rt) {
#pragma unroll
    for (int g = 0; g < 4; ++g) {
      float bi0 = bias[g * 32 + m];
      float bi1 = bias[g * 32 + 16 + m];
#pragma unroll
      for (int j = 0; j < 4; ++j) {
        float v0 = fmaxf(acc[rt][2 * g][j] + bi0, 0.f);
        float v1 = fmaxf(acc[rt][2 * g + 1][j] + bi1, 0.f);
        int r = rt * 16 + q * 4 + j;
        *(u32*)(hb + r * HSTR + g * 64 + m * 4) = pack2(v0, v1);
      }
    }
  }
}

// hidden layer 128->128: A from wave-private hb (physical k order), B from
// pre-permuted weights; result overwrites hb (all writes data-depend on all
// reads, so in-wave DS ordering makes single-buffer reuse safe).
__device__ __forceinline__ void layer_lds128(
    char* hb, const u16* __restrict__ Wp, const float* __restrict__ bias,
    int m, int q) {
  f32x4 acc[2][8];
#pragma unroll
  for (int rt = 0; rt < 2; ++rt)
#pragma unroll
    for (int ct = 0; ct < 8; ++ct)
      acc[rt][ct] = (f32x4){0.f, 0.f, 0.f, 0.f};

  const char* ab = hb + m * HSTR + q * 16;
  const u16* wb = Wp + m * 128 + q * 8;
#pragma unroll
  for (int ks = 0; ks < 4; ++ks) {
    bf16x8 b[8];
#pragma unroll
    for (int ct = 0; ct < 8; ++ct)
      b[ct] = *(const bf16x8*)(wb + ct * 2048 + ks * 32);
#pragma unroll
    for (int rt = 0; rt < 2; ++rt) {
      bf16x8 a = *(const bf16x8*)(ab + rt * 16 * HSTR + ks * 64);
#pragma unroll
      for (int ct = 0; ct < 8; ++ct)
        acc[rt][ct] =
            __builtin_amdgcn_mfma_f32_16x16x32_bf16(a, b[ct], acc[rt][ct], 0, 0, 0);
    }
  }
  epilogue_relu_pack(hb, acc, bias, m, q);
}

__global__ __launch_bounds__(256, 3) void mlp_kernel(
    const float* __restrict__ x, const u16* __restrict__ ws,
    const float* __restrict__ b1, const float* __restrict__ b2,
    const float* __restrict__ b3, const float* __restrict__ b4,
    float* __restrict__ out) {
  __shared__ char smem[4 * 32 * HSTR];   // 34816 B: one 32x136B h-buf per wave

  const int tid = threadIdx.x;
  const int lane = tid & 63;
  const int wave = tid >> 6;
  const int m = lane & 15;
  const int q = lane >> 4;
  char* hb = smem + wave * (32 * HSTR);
  const size_t row0 = (size_t)blockIdx.x * 128 + wave * 32;

  // ---- layer 1: A straight from global (nontemporal) + cvt, B = W1 ----
  {
    f32x4 acc[2][8];
#pragma unroll
    for (int rt = 0; rt < 2; ++rt)
#pragma unroll
      for (int ct = 0; ct < 8; ++ct)
        acc[rt][ct] = (f32x4){0.f, 0.f, 0.f, 0.f};

    const float* xr0 = x + (row0 + m) * 196;
    const float* xr1 = xr0 + 16 * 196;
    const u16* wb = ws + WS_W1 + m * 224 + q * 8;

#pragma unroll
    for (int ks = 0; ks < 7; ++ks) {
      bf16x8 b[8];
#pragma unroll
      for (int ct = 0; ct < 8; ++ct)
        b[ct] = *(const bf16x8*)(wb + ct * 3584 + ks * 32);

      bf16x8 a[2];
      if (ks < 6) {
        const vf4* p0 = (const vf4*)(xr0 + ks * 32 + q * 8);
        const vf4* p1 = (const vf4*)(xr1 + ks * 32 + q * 8);
        vf4 u0 = __builtin_nontemporal_load(p0);
        vf4 u1 = __builtin_nontemporal_load(p0 + 1);
        vf4 v0 = __builtin_nontemporal_load(p1);
        vf4 v1 = __builtin_nontemporal_load(p1 + 1);
        a[0] = cvt_frag(u0, u1);
        a[1] = cvt_frag(v0, v1);
      } else {  // k = 192..196 valid only (q==0, low half)
        vf4 z = (vf4){0.f, 0.f, 0.f, 0.f};
        vf4 u0 = z, v0 = z;
        if (q == 0) {
          u0 = __builtin_nontemporal_load((const vf4*)(xr0 + 192));
          v0 = __builtin_nontemporal_load((const vf4*)(xr1 + 192));
        }
        a[0] = cvt_frag(u0, z);
        a[1] = cvt_frag(v0, z);
      }
#pragma unroll
      for (int rt = 0; rt < 2; ++rt)
#pragma unroll
        for (int ct = 0; ct < 8; ++ct)
          acc[rt][ct] =
              __builtin_amdgcn_mfma_f32_16x16x32_bf16(a[rt], b[ct], acc[rt][ct], 0, 0, 0);
    }
    epilogue_relu_pack(hb, acc, b1, m, q);
  }

  // ---- layers 2, 3 (wave-private, no barriers) ----
  layer_lds128(hb, ws + WS_W2, b2, m, q);
  layer_lds128(hb, ws + WS_W3, b3, m, q);

  // ---- layer 4: [32,128] x W4p[16][128] -> out[32][10] fp32 ----
  {
    const u16* wb = ws + WS_W4 + m * 128 + q * 8;
    const char* ab = hb + m * HSTR + q * 16;
#pragma unroll
    for (int rt = 0; rt < 2; ++rt) {
      f32x4 acc = (f32x4){0.f, 0.f, 0.f, 0.f};
#pragma unroll
      for (int ks = 0; ks < 4; ++ks) {
        bf16x8 a = *(const bf16x8*)(ab + rt * 16 * HSTR + ks * 64);
        bf16x8 b = *(const bf16x8*)(wb + ks * 32);
        acc = __builtin_amdgcn_mfma_f32_16x16x32_bf16(a, b, acc, 0, 0, 0);
      }
      if (m < 10) {
        float bi = b4[m];
#pragma unroll
        for (int j = 0; j < 4; ++j) {
          size_t r = row0 + rt * 16 + q * 4 + j;
          out[r * 10 + m] = acc[j] + bi;
        }
      }
    }
  }
}

extern "C" void kernel_launch(void* const* d_in, const int* in_sizes, int n_in,
                              void* d_out, int out_size, void* d_ws, size_t ws_size,
                              hipStream_t stream) {
  const float* x  = (const float*)d_in[0];
  const float* W1 = (const float*)d_in[1];
  const float* b1 = (const float*)d_in[2];
  const float* W2 = (const float*)d_in[3];
  const float* b2 = (const float*)d_in[4];
  const float* W3 = (const float*)d_in[5];
  const float* b3 = (const float*)d_in[6];
  const float* W4 = (const float*)d_in[7];
  const float* b4 = (const float*)d_in[8];
  u16* ws = (u16*)d_ws;          // needs 126976 B
  float* out = (float*)d_out;

  prep_kernel<<<248, 256, 0, stream>>>(W1, W2, W3, W4, ws);
  // 524288 rows / 128 rows-per-block = 4096 blocks, 4 independent waves each
  mlp_kernel<<<4096, 256, 0, stream>>>(x, ws, b1, b2, b3, b4, out);
}